// Round 5
// baseline (290.658 us; speedup 1.0000x reference)
//
#include <hip/hip_runtime.h>
#include <hip/hip_bf16.h>
#include <float.h>
#include <math.h>

#define N 4096
#define DIN 64

typedef signed char i8_t;
typedef signed char i8x4 __attribute__((ext_vector_type(4)));
typedef int i32x4 __attribute__((ext_vector_type(4)));
typedef float f32x4 __attribute__((ext_vector_type(4)));

// ---------- async global->LDS, 16B per lane ----------
__device__ __forceinline__ void gload16(const void* g, void* l) {
    __builtin_amdgcn_global_load_lds((const __attribute__((address_space(1))) void*)g,
                                     (__attribute__((address_space(3))) void*)l,
                                     16, 0, 0);
}

__device__ __forceinline__ float block_reduce_sum(float s) {
    __shared__ float red[4];
    #pragma unroll
    for (int off = 32; off; off >>= 1) s += __shfl_down(s, off);
    if ((threadIdx.x & 63) == 0) red[threadIdx.x >> 6] = s;
    __syncthreads();
    return red[0] + red[1] + red[2] + red[3];
}

// ---------- top-4 insertion with tie -> lower index ----------
__device__ __forceinline__ bool better(float v1, int j1, float v2, int j2) {
    return v1 > v2 || (v1 == v2 && j1 < j2);
}
__device__ __forceinline__ void ins4(float v, int j, float bv[4], int bj[4]) {
    if (!better(v, j, bv[3], bj[3])) return;
    bv[3] = v; bj[3] = j;
    if (better(bv[3], bj[3], bv[2], bj[2])) {
        float tv = bv[2]; int tj = bj[2]; bv[2] = bv[3]; bj[2] = bj[3]; bv[3] = tv; bj[3] = tj;
    }
    if (better(bv[2], bj[2], bv[1], bj[1])) {
        float tv = bv[1]; int tj = bj[1]; bv[1] = bv[2]; bj[1] = bj[2]; bv[2] = tv; bj[2] = tj;
    }
    if (better(bv[1], bj[1], bv[0], bj[0])) {
        float tv = bv[0]; int tj = bj[0]; bv[0] = bv[1]; bj[0] = bj[1]; bv[1] = tv; bj[1] = tj;
    }
}

// ---------- K1: fused pre-pass ----------
// blocks [0,4096): rowsum of A -> dinv = 1/sqrt(d); zero rowsumP; atomicMax dmax
//   (dmax folded in via uint-bits atomicMax: dinv > 0 so float order == uint order;
//    dmaxf zeroed by hipMemsetAsync before this kernel)
// blocks [4096,5120): XW = x @ W^T (4 rows per block)
__global__ __launch_bounds__(256) void k_pre(const float* __restrict__ A,
                                             const float* __restrict__ x,
                                             const float* __restrict__ W,
                                             float* __restrict__ dinv,
                                             float* __restrict__ rowsumP,
                                             float* __restrict__ dmaxf,
                                             float* __restrict__ XW) {
    int tid = threadIdx.x;
    if (blockIdx.x >= N) {
        // ---- XW part ----
        __shared__ float Wl[64][65];   // padded: conflict-free
        __shared__ float xs[4][64];
        int bx = blockIdx.x - N;
        for (int i = tid; i < 64 * 64; i += 256) Wl[i >> 6][i & 63] = W[i];
        int r = tid >> 6, o = tid & 63;
        int row = bx * 4 + r;
        xs[r][o] = x[(size_t)row * DIN + o];
        __syncthreads();
        float acc = 0.f;
        #pragma unroll
        for (int d = 0; d < 64; d++) acc += xs[r][d] * Wl[o][d];
        XW[(size_t)row * DIN + o] = acc;
        return;
    }
    int row = blockIdx.x;
    const float4* a4 = (const float4*)(A + (size_t)row * N);
    float s = 0.f;
    for (int j = tid; j < N / 4; j += 256) {
        float4 v = a4[j];
        s += v.x + v.y + v.z + v.w;
    }
    float tot = block_reduce_sum(s);
    if (tid == 0) {
        float v = rsqrtf(tot);
        dinv[row] = v;
        rowsumP[row] = 0.f;  // init for k_gemm's atomics (ws is poisoned pre-launch)
        atomicMax((unsigned int*)dmaxf, __float_as_uint(v));
    }
}

// ---------- K3: Sq = i8(S), Tq = i8(S^T); q = rint(S * 127/dmax^2) ----------
__global__ __launch_bounds__(256) void k_make_sqt(const float* __restrict__ A,
                                                  const float* __restrict__ dinv,
                                                  const float* __restrict__ dmaxf,
                                                  i8_t* __restrict__ Sq,
                                                  i8_t* __restrict__ Tq) {
    __shared__ float tile[64][65];
    int tid = threadIdx.x;
    int c4 = tid & 15;   // column group (4 cols)
    int rg = tid >> 4;   // 0..15
    int i0 = blockIdx.y * 64;
    int j0 = blockIdx.x * 64;
    float dmax = *dmaxf;
    float sinv = 127.0f / (dmax * dmax);
    float4 dj = *(const float4*)(dinv + j0 + 4 * c4);
    #pragma unroll
    for (int rr = 0; rr < 4; rr++) {
        int r = rg + 16 * rr;
        int row = i0 + r;
        float di = dinv[row];
        float4 av = *(const float4*)(A + (size_t)row * N + j0 + 4 * c4);
        float s0 = av.x * di * dj.x, s1 = av.y * di * dj.y;
        float s2 = av.z * di * dj.z, s3 = av.w * di * dj.w;
        i8x4 qv;
        qv[0] = (i8_t)(int)fminf(rintf(s0 * sinv), 127.f);
        qv[1] = (i8_t)(int)fminf(rintf(s1 * sinv), 127.f);
        qv[2] = (i8_t)(int)fminf(rintf(s2 * sinv), 127.f);
        qv[3] = (i8_t)(int)fminf(rintf(s3 * sinv), 127.f);
        *(i8x4*)(Sq + (size_t)row * N + j0 + 4 * c4) = qv;
        tile[r][4 * c4 + 0] = s0;
        tile[r][4 * c4 + 1] = s1;
        tile[r][4 * c4 + 2] = s2;
        tile[r][4 * c4 + 3] = s3;
    }
    __syncthreads();
    #pragma unroll
    for (int cc = 0; cc < 4; cc++) {
        int c = rg + 16 * cc;
        int gj = j0 + c;
        i8x4 qv;
        #pragma unroll
        for (int u = 0; u < 4; u++)
            qv[u] = (i8_t)(int)fminf(rintf(tile[4 * c4 + u][c] * sinv), 127.f);
        *(i8x4*)(Tq + (size_t)gj * N + i0 + 4 * c4) = qv;
    }
}

// ---------- K4: int8 GEMM (256x256 tile) + fused epilogue ----------
// R9: loop reverted to the R3 2-phase (4-phase was NULL; MfmaUtil pinned at 25%
// across 4 structurally different loops -> loop is not the lever). Epilogue
// de-VMEM'd: the 128 scalar global byte loads of Sq per thread (16.7M/dispatch,
// VMEM-issue + L2-latency bound) are replaced by ONE cooperative 64KB LDS stage
// of the needed Sq[bi*256..][bj*256..] block (8x gload16/thread, coalesced,
// source-XOR-swizzled by (row>>2)&3 so the per-fragment ds_read_u8 is
// bank-conflict-free: quads read distinct chunks). LDS back to 67.6KB.
__global__ __launch_bounds__(512, 2) void k_gemm(const i8_t* __restrict__ Sq,
                                                 const i8_t* __restrict__ Tq,
                                                 const float* __restrict__ dmaxf,
                                                 const float* __restrict__ theta,
                                                 float* __restrict__ rowsumP,
                                                 float* __restrict__ candV,
                                                 int* __restrict__ candJ) {
    // sequential reuse: staging dbuf 2x32KB -> SqD 64KB -> pbuf 67.6KB
    __shared__ __attribute__((aligned(128))) i8_t smem[67584];
    float (*pbuf)[264] = (float (*)[264])smem;

    int tid = threadIdx.x;
    int lane = tid & 63;
    int wave = tid >> 6;
    int wr = wave >> 2;          // 0..1  (row half: 128 rows)
    int wc = wave & 3;           // 0..3  (col quarter: 64 cols)

    // XCD-chunked swizzle on the 16x16 grid (kept; cheap)
    int bid = blockIdx.x;
    int xcd = bid & 7, local = bid >> 3;               // local 0..31
    int bi = ((xcd & 1) << 3) + (local & 7);           // 0..15
    int bj = ((xcd >> 1) << 2) + (local >> 3);         // 0..15

    // staging: thread t -> row (t>>2 [+128]), chunk (t&3); 16B chunks.
    // Source-XOR swizzle so LDS stays linear per-lane.
    int qoff = ((tid & 3) ^ ((tid >> 3) & 3)) * 16;
    int row0 = tid >> 2;                               // 0..127
    const i8_t* Ag0 = Sq + (size_t)(bi * 256 + row0) * N + qoff;
    const i8_t* Ag1 = Sq + (size_t)(bi * 256 + 128 + row0) * N + qoff;
    const i8_t* Bg0 = Tq + (size_t)(bj * 256 + row0) * N + qoff;
    const i8_t* Bg1 = Tq + (size_t)(bj * 256 + 128 + row0) * N + qoff;
    int l0 = tid * 16;            // rows 0..127 region
    int l1 = (tid + 512) * 16;    // rows 128..255

    i32x4 acc[8][4];
    i32x4 z = {0, 0, 0, 0};
    #pragma unroll
    for (int i = 0; i < 8; i++)
        #pragma unroll
        for (int j = 0; j < 4; j++) acc[i][j] = z;

    int r = lane & 15, q = lane >> 4;
    int qs = q ^ ((r >> 1) & 3);  // fragment-read swizzle matches staging swizzle
    int aoff = (wr * 128 + r) * 64 + qs * 16;
    int boff = (wc * 64 + r) * 64 + qs * 16;

    // prologue: stage K-tile 0 into buffer 0
    gload16(Ag0, smem + l0);
    gload16(Ag1, smem + l1);
    gload16(Bg0, smem + 16384 + l0);
    gload16(Bg1, smem + 16384 + l1);

    int p = 0;
    for (int t = 0; t < N / 64; ++t) {
        int k1 = (t + 1) * 64;
        if (k1 < N) {
            i8_t* d = smem + (p ^ 1) * 32768;
            gload16(Ag0 + k1, d + l0);
            gload16(Ag1 + k1, d + l1);
            gload16(Bg0 + k1, d + 16384 + l0);
            gload16(Bg1 + k1, d + 16384 + l1);
            // tile t's 4 loads (oldest) done; tile t+1's 4 stay in flight
            asm volatile("s_waitcnt vmcnt(4)" ::: "memory");
        } else {
            asm volatile("s_waitcnt vmcnt(0)" ::: "memory");
        }
        __builtin_amdgcn_s_barrier();

        const i8_t* Ab = smem + p * 32768;
        const i8_t* Bb = Ab + 16384;
        i32x4 af[8], bfr[4];
        #pragma unroll
        for (int mi = 0; mi < 8; mi++) af[mi] = *(const i32x4*)(Ab + aoff + mi * 16 * 64);
        #pragma unroll
        for (int ni = 0; ni < 4; ni++) bfr[ni] = *(const i32x4*)(Bb + boff + ni * 16 * 64);

        __builtin_amdgcn_s_setprio(1);
        #pragma unroll
        for (int mi = 0; mi < 8; mi++)
            #pragma unroll
            for (int ni = 0; ni < 4; ni++)
                acc[mi][ni] = __builtin_amdgcn_mfma_i32_16x16x64_i8(af[mi], bfr[ni],
                                                                    acc[mi][ni], 0, 0, 0);
        __builtin_amdgcn_s_setprio(0);

        // our ds_reads of buf[p] must finish before next iter's stage overwrites it
        asm volatile("s_waitcnt lgkmcnt(0)" ::: "memory");
        __builtin_amdgcn_s_barrier();
        p ^= 1;
    }
    // loop exit: vmcnt==0 (t=63 drained), all waves past lgkmcnt(0)+barrier
    // -> staging region dead.

    // ---- SqD stage: Sq[bi*256..+256)[bj*256..+256) (64KB) into smem[0..64K) ----
    // LDS slot (row, chunk c) holds global chunk c ^ ((row>>2)&3): quads then
    // read distinct chunks -> conflict-free ds_read_u8 in the epilogue.
    #pragma unroll
    for (int u = 0; u < 8; u++) {
        int o = (u * 512 + tid) * 16;          // wave-uniform base + lane*16
        int rrow = o >> 8;                     // 0..255
        int ch = (o >> 4) & 15;
        int sch = ch ^ ((rrow >> 2) & 3);
        gload16(Sq + (size_t)(bi * 256 + rrow) * N + bj * 256 + sch * 16, smem + o);
    }
    asm volatile("s_waitcnt vmcnt(0)" ::: "memory");
    __syncthreads();

    // ---- epilogue: p = t1s2*acc + t0s*SqD + I, in place of acc ----
    float dmax = *dmaxf;
    float sq = dmax * dmax / 127.0f;
    float t0 = 1.f / (1.f + expf(-theta[0]));
    float t1 = 1.f / (1.f + expf(-theta[1]));
    float t0s = t0 * sq;
    float t1s2 = t1 * sq * sq;
    int col = lane & 15, quad = lane >> 4;

    #pragma unroll
    for (int mi = 0; mi < 8; mi++) {
        int lrow0 = wr * 128 + mi * 16 + quad * 4;
        int gi0 = bi * 256 + lrow0;
        float rsum[4] = {0.f, 0.f, 0.f, 0.f};
        #pragma unroll
        for (int ni = 0; ni < 4; ni++) {
            int colb = wc * 64 + ni * 16 + col;
            int gj = bj * 256 + colb;
            f32x4 pf;
            #pragma unroll
            for (int rr = 0; rr < 4; rr++) {
                int lrow = lrow0 + rr;
                int ch = (colb >> 4) ^ ((lrow >> 2) & 3);
                float qv = (float)smem[lrow * 256 + ch * 16 + col];  // t0 term (LDS)
                float p2 = t1s2 * (float)acc[mi][ni][rr] + t0s * qv
                           + ((gi0 + rr == gj) ? 1.f : 0.f);
                pf[rr] = p2;
                rsum[rr] += p2;
            }
            acc[mi][ni] = __builtin_bit_cast(i32x4, pf);
        }
        #pragma unroll
        for (int rr = 0; rr < 4; rr++) {
            float v = rsum[rr];
            v += __shfl_xor(v, 1);
            v += __shfl_xor(v, 2);
            v += __shfl_xor(v, 4);
            v += __shfl_xor(v, 8);
            if (col == 0) atomicAdd(&rowsumP[gi0 + rr], v);
        }
    }

    // ---- 4 row-quarter passes: store 64x256 slab -> scan top-4 per row ----
    int srow = tid >> 3;        // 0..63: scan row within pass
    int sub = tid & 7;          // 8 threads per row, stride-8 column interleave
    __syncthreads();            // all waves done reading SqD; pbuf may overwrite

    #pragma unroll
    for (int pass = 0; pass < 4; pass++) {
        if (wr == (pass >> 1)) {
            int mi0 = (pass & 1) * 4;
            #pragma unroll
            for (int m2 = 0; m2 < 4; m2++) {
                #pragma unroll
                for (int ni = 0; ni < 4; ni++) {
                    f32x4 pf = __builtin_bit_cast(f32x4, acc[mi0 + m2][ni]);
                    #pragma unroll
                    for (int rr = 0; rr < 4; rr++)
                        pbuf[m2 * 16 + quad * 4 + rr][wc * 64 + ni * 16 + col] = pf[rr];
                }
            }
        }
        __syncthreads();
        float bv[4] = {-FLT_MAX, -FLT_MAX, -FLT_MAX, -FLT_MAX};
        int bjx[4] = {N, N, N, N};
        int jbase = bj * 256;
        for (int i = 0; i < 32; i++) {
            int c = i * 8 + sub;
            ins4(pbuf[srow][c], jbase + c, bv, bjx);
        }
        // merge the 8 sub-scans of this row (disjoint col sets each step)
        #pragma unroll
        for (int off = 1; off < 8; off <<= 1) {
            float ov[4]; int oj[4];
            #pragma unroll
            for (int c = 0; c < 4; c++) { ov[c] = __shfl_xor(bv[c], off); oj[c] = __shfl_xor(bjx[c], off); }
            #pragma unroll
            for (int c = 0; c < 4; c++) ins4(ov[c], oj[c], bv, bjx);
        }
        if (sub == 0) {
            size_t base = ((size_t)(bi * 256 + pass * 64 + srow) * 16 + bj) * 4;
            #pragma unroll
            for (int c = 0; c < 4; c++) { candV[base + c] = bv[c]; candJ[base + c] = bjx[c]; }
        }
        __syncthreads();
    }
}

// ---------- K6: per-row final top-4 + gather of XW; 4 rows per 256-thr block ----
// dinv2 computed inline as rsqrtf(rowsumP[.]) -- k_dinv2 kernel eliminated.
__global__ __launch_bounds__(256) void k_final(const float* __restrict__ candV,
                                               const int* __restrict__ candJ,
                                               const float* __restrict__ rowsumP,
                                               const float* __restrict__ XW,
                                               const float* __restrict__ bvec,
                                               const int* __restrict__ kin,
                                               float* __restrict__ out) {
    int tid = threadIdx.x;
    int row = blockIdx.x * 4 + (tid >> 6);
    int t = tid & 63;
    float cv = candV[(size_t)row * 64 + t];
    int cj = candJ[(size_t)row * 64 + t];
    float bv[4] = {-FLT_MAX, -FLT_MAX, -FLT_MAX, -FLT_MAX};
    int bj[4] = {N, N, N, N};
    ins4(cv * rsqrtf(rowsumP[cj]), cj, bv, bj);
    // butterfly merge across 64 lanes (disjoint sets at every step)
    #pragma unroll
    for (int off = 1; off < 64; off <<= 1) {
        float ov[4]; int oj[4];
        #pragma unroll
        for (int c = 0; c < 4; c++) { ov[c] = __shfl_xor(bv[c], off); oj[c] = __shfl_xor(bj[c], off); }
        #pragma unroll
        for (int c = 0; c < 4; c++) ins4(ov[c], oj[c], bv, bj);
    }
    int kk = kin[0];
    if (kk > 4) kk = 4;
    if (kk < 0) kk = 0;
    float sc = rsqrtf(rowsumP[row]);
    float o = bvec[t];
    for (int c = 0; c < kk; c++)
        o += sc * bv[c] * XW[(size_t)bj[c] * DIN + t];
    out[(size_t)row * DIN + t] = o;
}

extern "C" void kernel_launch(void* const* d_in, const int* in_sizes, int n_in,
                              void* d_out, int out_size, void* d_ws, size_t ws_size,
                              hipStream_t stream) {
    const float* x = (const float*)d_in[0];
    const float* A = (const float*)d_in[1];
    const float* theta = (const float*)d_in[2];
    const float* W = (const float*)d_in[3];
    const float* b = (const float*)d_in[4];
    const int* kin = (const int*)d_in[5];
    float* out = (float*)d_out;

    // workspace layout (~35.3 MB)
    char* ws = (char*)d_ws;
    i8_t* Sq = (i8_t*)ws;                                   // 16 MB
    i8_t* Tq = (i8_t*)(ws + (size_t)N * N);                 // 16 MB
    float* candV = (float*)(ws + (size_t)N * N * 2);        // 1 MB (N x 64)
    int* candJ = (int*)(ws + (size_t)N * N * 2 + (size_t)N * 64 * 4);  // 1 MB
    float* dinv = (float*)(ws + (size_t)N * N * 2 + (size_t)N * 64 * 8);
    float* rowsumP = dinv + N;
    float* dmaxf = rowsumP + N;
    float* XW = (float*)(ws + (size_t)N * N * 2 + (size_t)N * 64 * 8 + 65536);  // 1 MB

    hipMemsetAsync(dmaxf, 0, 4, stream);  // atomicMax identity for k_pre
    k_pre<<<N + N / 4, 256, 0, stream>>>(A, x, W, dinv, rowsumP, dmaxf, XW);
    k_make_sqt<<<dim3(64, 64), 256, 0, stream>>>(A, dinv, dmaxf, Sq, Tq);
    k_gemm<<<256, 512, 0, stream>>>(Sq, Tq, dmaxf, theta, rowsumP, candV, candJ);
    k_final<<<N / 4, 256, 0, stream>>>(candV, candJ, rowsumP, XW, b, kin, out);
}

// Round 6
// 244.065 us; speedup vs baseline: 1.1909x; 1.1909x over previous
//
#include <hip/hip_runtime.h>
#include <hip/hip_bf16.h>
#include <float.h>
#include <math.h>

#define N 4096
#define DIN 64

typedef signed char i8_t;
typedef signed char i8x4 __attribute__((ext_vector_type(4)));
typedef int i32x4 __attribute__((ext_vector_type(4)));
typedef float f32x4 __attribute__((ext_vector_type(4)));

// ---------- async global->LDS, 16B per lane ----------
__device__ __forceinline__ void gload16(const void* g, void* l) {
    __builtin_amdgcn_global_load_lds((const __attribute__((address_space(1))) void*)g,
                                     (__attribute__((address_space(3))) void*)l,
                                     16, 0, 0);
}

__device__ __forceinline__ float block_reduce_sum(float s) {
    __shared__ float red[4];
    #pragma unroll
    for (int off = 32; off; off >>= 1) s += __shfl_down(s, off);
    if ((threadIdx.x & 63) == 0) red[threadIdx.x >> 6] = s;
    __syncthreads();
    return red[0] + red[1] + red[2] + red[3];
}

// ---------- top-4 insertion with tie -> lower index ----------
__device__ __forceinline__ bool better(float v1, int j1, float v2, int j2) {
    return v1 > v2 || (v1 == v2 && j1 < j2);
}
__device__ __forceinline__ void ins4(float v, int j, float bv[4], int bj[4]) {
    if (!better(v, j, bv[3], bj[3])) return;
    bv[3] = v; bj[3] = j;
    if (better(bv[3], bj[3], bv[2], bj[2])) {
        float tv = bv[2]; int tj = bj[2]; bv[2] = bv[3]; bj[2] = bj[3]; bv[3] = tv; bj[3] = tj;
    }
    if (better(bv[2], bj[2], bv[1], bj[1])) {
        float tv = bv[1]; int tj = bj[1]; bv[1] = bv[2]; bj[1] = bj[2]; bv[2] = tv; bj[2] = tj;
    }
    if (better(bv[1], bj[1], bv[0], bj[0])) {
        float tv = bv[0]; int tj = bj[0]; bv[0] = bv[1]; bj[0] = bj[1]; bv[1] = tv; bj[1] = tj;
    }
}

// ---------- K1: rowsums of A -> dinv = 1/sqrt(d); also zero rowsumP ----------
__global__ __launch_bounds__(256) void k_rowsum_dinv(const float* __restrict__ A,
                                                     float* __restrict__ dinv,
                                                     float* __restrict__ rowsumP) {
    int row = blockIdx.x, tid = threadIdx.x;
    const float4* a4 = (const float4*)(A + (size_t)row * N);
    float s = 0.f;
    for (int j = tid; j < N / 4; j += 256) {
        float4 v = a4[j];
        s += v.x + v.y + v.z + v.w;
    }
    float tot = block_reduce_sum(s);
    if (tid == 0) {
        dinv[row] = rsqrtf(tot);
        rowsumP[row] = 0.f;  // init for k_gemm's atomics (ws is poisoned pre-launch)
    }
}

// ---------- K2: dmax = max(dinv), single block ----------
__global__ __launch_bounds__(1024) void k_dmax(const float* __restrict__ dinv,
                                               float* __restrict__ dmaxf) {
    int t = threadIdx.x;
    float m = fmaxf(fmaxf(dinv[t], dinv[t + 1024]), fmaxf(dinv[t + 2048], dinv[t + 3072]));
    #pragma unroll
    for (int off = 32; off; off >>= 1) m = fmaxf(m, __shfl_down(m, off));
    __shared__ float red[16];
    if ((t & 63) == 0) red[t >> 6] = m;
    __syncthreads();
    if (t == 0) {
        float mm = red[0];
        #pragma unroll
        for (int i = 1; i < 16; i++) mm = fmaxf(mm, red[i]);
        *dmaxf = mm;
    }
}

// ---------- K3: Sq = i8(S), Tq = i8(S^T); q = rint(S * 127/dmax^2) ----------
__global__ __launch_bounds__(256) void k_make_sqt(const float* __restrict__ A,
                                                  const float* __restrict__ dinv,
                                                  const float* __restrict__ dmaxf,
                                                  i8_t* __restrict__ Sq,
                                                  i8_t* __restrict__ Tq) {
    __shared__ float tile[64][65];
    int tid = threadIdx.x;
    int c4 = tid & 15;   // column group (4 cols)
    int rg = tid >> 4;   // 0..15
    int i0 = blockIdx.y * 64;
    int j0 = blockIdx.x * 64;
    float dmax = *dmaxf;
    float sinv = 127.0f / (dmax * dmax);
    float4 dj = *(const float4*)(dinv + j0 + 4 * c4);
    #pragma unroll
    for (int rr = 0; rr < 4; rr++) {
        int r = rg + 16 * rr;
        int row = i0 + r;
        float di = dinv[row];
        float4 av = *(const float4*)(A + (size_t)row * N + j0 + 4 * c4);
        float s0 = av.x * di * dj.x, s1 = av.y * di * dj.y;
        float s2 = av.z * di * dj.z, s3 = av.w * di * dj.w;
        i8x4 qv;
        qv[0] = (i8_t)(int)fminf(rintf(s0 * sinv), 127.f);
        qv[1] = (i8_t)(int)fminf(rintf(s1 * sinv), 127.f);
        qv[2] = (i8_t)(int)fminf(rintf(s2 * sinv), 127.f);
        qv[3] = (i8_t)(int)fminf(rintf(s3 * sinv), 127.f);
        *(i8x4*)(Sq + (size_t)row * N + j0 + 4 * c4) = qv;
        tile[r][4 * c4 + 0] = s0;
        tile[r][4 * c4 + 1] = s1;
        tile[r][4 * c4 + 2] = s2;
        tile[r][4 * c4 + 3] = s3;
    }
    __syncthreads();
    #pragma unroll
    for (int cc = 0; cc < 4; cc++) {
        int c = rg + 16 * cc;
        int gj = j0 + c;
        i8x4 qv;
        #pragma unroll
        for (int u = 0; u < 4; u++)
            qv[u] = (i8_t)(int)fminf(rintf(tile[4 * c4 + u][c] * sinv), 127.f);
        *(i8x4*)(Tq + (size_t)gj * N + i0 + 4 * c4) = qv;
    }
}

// ---------- K3b: XW = x @ W^T  (4096x64 @ 64x64) ----------
__global__ __launch_bounds__(256) void k_xw(const float* __restrict__ x,
                                            const float* __restrict__ W,
                                            float* __restrict__ XW) {
    __shared__ float Wl[64][65];   // padded: conflict-free
    __shared__ float xs[4][64];
    int tid = threadIdx.x;
    for (int i = tid; i < 64 * 64; i += 256) Wl[i >> 6][i & 63] = W[i];
    int r = tid >> 6, o = tid & 63;
    int row = blockIdx.x * 4 + r;
    xs[r][o] = x[(size_t)row * DIN + o];
    __syncthreads();
    float acc = 0.f;
    #pragma unroll
    for (int d = 0; d < 64; d++) acc += xs[r][d] * Wl[o][d];
    XW[(size_t)row * DIN + o] = acc;
}

// ---------- K4: int8 GEMM (256x256 tile) + fused epilogue ----------
// R10: 4-deep circular staging (prefetch distance 3, vmcnt(8) steady state).
// Evidence: staging throughput scales with resident blocks (R2: 4 blk/CU ->
// 16 B/cyc/CU; R3/R5: 1 blk/CU -> 9 B/cyc/CU) while barrier/phase structure
// changes are all NULL -> the K-loop is Little's-law-bound on in-flight
// global_load_lds bytes, not on L2 BW or sync overhead. 4 buffers triple the
// in-flight bytes at the wait point (64KB vs 32KB outstanding, 96KB after
// issue). Hazard audit: tile t+3 -> buf (t+3)&3 = (t-1)&3, issued only after
// barrier1 of iter t, by which point every wave passed iter t-1's lgkmcnt(0)
// + barrier2 (its reads of that buffer are drained). Tail: vmcnt(8/4/0) at
// t<=61 / 62 / 63. LDS = 4x32KB = 128KB, still 1 block/CU; SqD (64KB) and
// pbuf (67.6KB) alias the dead staging region after the loop.
__global__ __launch_bounds__(512, 2) void k_gemm(const i8_t* __restrict__ Sq,
                                                 const i8_t* __restrict__ Tq,
                                                 const float* __restrict__ dmaxf,
                                                 const float* __restrict__ theta,
                                                 float* __restrict__ rowsumP,
                                                 float* __restrict__ candV,
                                                 int* __restrict__ candJ) {
    __shared__ __attribute__((aligned(128))) i8_t smem[4 * 32768];  // 128 KB
    float (*pbuf)[264] = (float (*)[264])smem;

    int tid = threadIdx.x;
    int lane = tid & 63;
    int wave = tid >> 6;
    int wr = wave >> 2;          // 0..1  (row half: 128 rows)
    int wc = wave & 3;           // 0..3  (col quarter: 64 cols)

    // XCD-chunked swizzle on the 16x16 grid (kept; cheap)
    int bid = blockIdx.x;
    int xcd = bid & 7, local = bid >> 3;               // local 0..31
    int bi = ((xcd & 1) << 3) + (local & 7);           // 0..15
    int bj = ((xcd >> 1) << 2) + (local >> 3);         // 0..15

    // staging: thread t -> row (t>>2 [+128]), chunk (t&3); 16B chunks.
    // Source-XOR swizzle so LDS stays linear per-lane.
    int qoff = ((tid & 3) ^ ((tid >> 3) & 3)) * 16;
    int row0 = tid >> 2;                               // 0..127
    const i8_t* Ag0 = Sq + (size_t)(bi * 256 + row0) * N + qoff;
    const i8_t* Ag1 = Sq + (size_t)(bi * 256 + 128 + row0) * N + qoff;
    const i8_t* Bg0 = Tq + (size_t)(bj * 256 + row0) * N + qoff;
    const i8_t* Bg1 = Tq + (size_t)(bj * 256 + 128 + row0) * N + qoff;
    int l0 = tid * 16;            // rows 0..127 region
    int l1 = (tid + 512) * 16;    // rows 128..255

    i32x4 acc[8][4];
    i32x4 z = {0, 0, 0, 0};
    #pragma unroll
    for (int i = 0; i < 8; i++)
        #pragma unroll
        for (int j = 0; j < 4; j++) acc[i][j] = z;

    int r = lane & 15, q = lane >> 4;
    int qs = q ^ ((r >> 1) & 3);  // fragment-read swizzle matches staging swizzle
    int aoff = (wr * 128 + r) * 64 + qs * 16;
    int boff = (wc * 64 + r) * 64 + qs * 16;

    // prologue: stage K-tiles 0,1,2 into buffers 0,1,2
    #pragma unroll
    for (int pt = 0; pt < 3; ++pt) {
        i8_t* d = smem + pt * 32768;
        gload16(Ag0 + pt * 64, d + l0);
        gload16(Ag1 + pt * 64, d + l1);
        gload16(Bg0 + pt * 64, d + 16384 + l0);
        gload16(Bg1 + pt * 64, d + 16384 + l1);
    }

    for (int t = 0; t < N / 64; ++t) {
        // ensure tile t's 4 loads done; keep later tiles' loads in flight
        if (t <= 61)      { asm volatile("s_waitcnt vmcnt(8)" ::: "memory"); }
        else if (t == 62) { asm volatile("s_waitcnt vmcnt(4)" ::: "memory"); }
        else              { asm volatile("s_waitcnt vmcnt(0)" ::: "memory"); }
        __builtin_amdgcn_s_barrier();

        // issue tile t+3 into buf (t+3)&3 == (t-1)&3 (free: all waves passed
        // iter t-1's lgkmcnt(0)+barrier before this point)
        if (t + 3 < N / 64) {
            i8_t* d = smem + ((t + 3) & 3) * 32768;
            int k3 = (t + 3) * 64;
            gload16(Ag0 + k3, d + l0);
            gload16(Ag1 + k3, d + l1);
            gload16(Bg0 + k3, d + 16384 + l0);
            gload16(Bg1 + k3, d + 16384 + l1);
        }

        const i8_t* Ab = smem + (t & 3) * 32768;
        const i8_t* Bb = Ab + 16384;
        i32x4 af[8], bfr[4];
        #pragma unroll
        for (int mi = 0; mi < 8; mi++) af[mi] = *(const i32x4*)(Ab + aoff + mi * 16 * 64);
        #pragma unroll
        for (int ni = 0; ni < 4; ni++) bfr[ni] = *(const i32x4*)(Bb + boff + ni * 16 * 64);

        __builtin_amdgcn_s_setprio(1);
        #pragma unroll
        for (int mi = 0; mi < 8; mi++)
            #pragma unroll
            for (int ni = 0; ni < 4; ni++)
                acc[mi][ni] = __builtin_amdgcn_mfma_i32_16x16x64_i8(af[mi], bfr[ni],
                                                                    acc[mi][ni], 0, 0, 0);
        __builtin_amdgcn_s_setprio(0);

        // our ds_reads of buf[t&3] must finish before it is overwritten (iter t+1
        // issues tile t+4 into buf (t+4)&3; buf t&3 is overwritten at iter t+1... t+3)
        asm volatile("s_waitcnt lgkmcnt(0)" ::: "memory");
        __builtin_amdgcn_s_barrier();
    }
    // loop exit: vmcnt==0 (t=63), all waves past lgkmcnt(0)+barrier -> staging dead.

    // ---- SqD stage: Sq[bi*256..+256)[bj*256..+256) (64KB) into smem[0..64K) ----
    // LDS slot (row, chunk c) holds global chunk c ^ ((row>>2)&3): quads then
    // read distinct chunks -> conflict-free ds_read_u8 in the epilogue.
    #pragma unroll
    for (int u = 0; u < 8; u++) {
        int o = (u * 512 + tid) * 16;          // wave-uniform base + lane*16
        int rrow = o >> 8;                     // 0..255
        int ch = (o >> 4) & 15;
        int sch = ch ^ ((rrow >> 2) & 3);
        gload16(Sq + (size_t)(bi * 256 + rrow) * N + bj * 256 + sch * 16, smem + o);
    }
    asm volatile("s_waitcnt vmcnt(0)" ::: "memory");
    __syncthreads();

    // ---- epilogue: p = t1s2*acc + t0s*SqD + I, in place of acc ----
    float dmax = *dmaxf;
    float sq = dmax * dmax / 127.0f;
    float t0 = 1.f / (1.f + expf(-theta[0]));
    float t1 = 1.f / (1.f + expf(-theta[1]));
    float t0s = t0 * sq;
    float t1s2 = t1 * sq * sq;
    int col = lane & 15, quad = lane >> 4;

    #pragma unroll
    for (int mi = 0; mi < 8; mi++) {
        int lrow0 = wr * 128 + mi * 16 + quad * 4;
        int gi0 = bi * 256 + lrow0;
        float rsum[4] = {0.f, 0.f, 0.f, 0.f};
        #pragma unroll
        for (int ni = 0; ni < 4; ni++) {
            int colb = wc * 64 + ni * 16 + col;
            int gj = bj * 256 + colb;
            f32x4 pf;
            #pragma unroll
            for (int rr = 0; rr < 4; rr++) {
                int lrow = lrow0 + rr;
                int ch = ((colb >> 4) ^ ((lrow >> 2) & 3));
                float qv = (float)smem[lrow * 256 + ch * 16 + col];  // t0 term (LDS)
                float p2 = t1s2 * (float)acc[mi][ni][rr] + t0s * qv
                           + ((gi0 + rr == gj) ? 1.f : 0.f);
                pf[rr] = p2;
                rsum[rr] += p2;
            }
            acc[mi][ni] = __builtin_bit_cast(i32x4, pf);
        }
        #pragma unroll
        for (int rr = 0; rr < 4; rr++) {
            float v = rsum[rr];
            v += __shfl_xor(v, 1);
            v += __shfl_xor(v, 2);
            v += __shfl_xor(v, 4);
            v += __shfl_xor(v, 8);
            if (col == 0) atomicAdd(&rowsumP[gi0 + rr], v);
        }
    }

    // ---- 4 row-quarter passes: store 64x256 slab -> scan top-4 per row ----
    int srow = tid >> 3;        // 0..63: scan row within pass
    int sub = tid & 7;          // 8 threads per row, stride-8 column interleave
    __syncthreads();            // all waves done reading SqD; pbuf may overwrite

    #pragma unroll
    for (int pass = 0; pass < 4; pass++) {
        if (wr == (pass >> 1)) {
            int mi0 = (pass & 1) * 4;
            #pragma unroll
            for (int m2 = 0; m2 < 4; m2++) {
                #pragma unroll
                for (int ni = 0; ni < 4; ni++) {
                    f32x4 pf = __builtin_bit_cast(f32x4, acc[mi0 + m2][ni]);
                    #pragma unroll
                    for (int rr = 0; rr < 4; rr++)
                        pbuf[m2 * 16 + quad * 4 + rr][wc * 64 + ni * 16 + col] = pf[rr];
                }
            }
        }
        __syncthreads();
        float bv[4] = {-FLT_MAX, -FLT_MAX, -FLT_MAX, -FLT_MAX};
        int bjx[4] = {N, N, N, N};
        int jbase = bj * 256;
        for (int i = 0; i < 32; i++) {
            int c = i * 8 + sub;
            ins4(pbuf[srow][c], jbase + c, bv, bjx);
        }
        // merge the 8 sub-scans of this row (disjoint col sets each step)
        #pragma unroll
        for (int off = 1; off < 8; off <<= 1) {
            float ov[4]; int oj[4];
            #pragma unroll
            for (int c = 0; c < 4; c++) { ov[c] = __shfl_xor(bv[c], off); oj[c] = __shfl_xor(bjx[c], off); }
            #pragma unroll
            for (int c = 0; c < 4; c++) ins4(ov[c], oj[c], bv, bjx);
        }
        if (sub == 0) {
            size_t base = ((size_t)(bi * 256 + pass * 64 + srow) * 16 + bj) * 4;
            #pragma unroll
            for (int c = 0; c < 4; c++) { candV[base + c] = bv[c]; candJ[base + c] = bjx[c]; }
        }
        __syncthreads();
    }
}

// ---------- K5: dinv2 = rsqrt(rowsumP) ----------
__global__ __launch_bounds__(256) void k_dinv2(const float* __restrict__ rowsumP,
                                               float* __restrict__ dinv2) {
    int g = blockIdx.x * 256 + threadIdx.x;
    dinv2[g] = rsqrtf(rowsumP[g]);
}

// ---------- K6: per-row final top-4 (exact dinv2 scaling) + gather of XW ----------
// 64 candidates/row (16 col-blocks x 4); 64 threads x 1 candidate each.
__global__ __launch_bounds__(64) void k_final(const float* __restrict__ candV,
                                              const int* __restrict__ candJ,
                                              const float* __restrict__ dinv2,
                                              const float* __restrict__ XW,
                                              const float* __restrict__ bvec,
                                              const int* __restrict__ kin,
                                              float* __restrict__ out) {
    int row = blockIdx.x, t = threadIdx.x;
    float cv = candV[(size_t)row * 64 + t];
    int cj = candJ[(size_t)row * 64 + t];
    float bv[4] = {-FLT_MAX, -FLT_MAX, -FLT_MAX, -FLT_MAX};
    int bj[4] = {N, N, N, N};
    ins4(cv * dinv2[cj], cj, bv, bj);
    // butterfly merge across 64 lanes (disjoint sets at every step)
    #pragma unroll
    for (int off = 1; off < 64; off <<= 1) {
        float ov[4]; int oj[4];
        #pragma unroll
        for (int c = 0; c < 4; c++) { ov[c] = __shfl_xor(bv[c], off); oj[c] = __shfl_xor(bj[c], off); }
        #pragma unroll
        for (int c = 0; c < 4; c++) ins4(ov[c], oj[c], bv, bj);
    }
    int kk = kin[0];
    if (kk > 4) kk = 4;
    if (kk < 0) kk = 0;
    float sc = dinv2[row];
    float o = bvec[t];
    for (int c = 0; c < kk; c++)
        o += sc * bv[c] * XW[(size_t)bj[c] * DIN + t];
    out[(size_t)row * DIN + t] = o;
}

extern "C" void kernel_launch(void* const* d_in, const int* in_sizes, int n_in,
                              void* d_out, int out_size, void* d_ws, size_t ws_size,
                              hipStream_t stream) {
    const float* x = (const float*)d_in[0];
    const float* A = (const float*)d_in[1];
    const float* theta = (const float*)d_in[2];
    const float* W = (const float*)d_in[3];
    const float* b = (const float*)d_in[4];
    const int* kin = (const int*)d_in[5];
    float* out = (float*)d_out;

    // workspace layout (~35.3 MB)
    char* ws = (char*)d_ws;
    i8_t* Sq = (i8_t*)ws;                                   // 16 MB
    i8_t* Tq = (i8_t*)(ws + (size_t)N * N);                 // 16 MB
    float* candV = (float*)(ws + (size_t)N * N * 2);        // 1 MB (N x 64)
    int* candJ = (int*)(ws + (size_t)N * N * 2 + (size_t)N * 64 * 4);  // 1 MB
    float* dinv = (float*)(ws + (size_t)N * N * 2 + (size_t)N * 64 * 8);
    float* dinv2 = dinv + N;
    float* rowsumP = dinv2 + N;
    float* dmaxf = rowsumP + N;
    float* XW = (float*)(ws + (size_t)N * N * 2 + (size_t)N * 64 * 8 + 65536);  // 1 MB

    k_xw<<<N / 4, 256, 0, stream>>>(x, W, XW);
    k_rowsum_dinv<<<N, 256, 0, stream>>>(A, dinv, rowsumP);
    k_dmax<<<1, 1024, 0, stream>>>(dinv, dmaxf);
    k_make_sqt<<<dim3(64, 64), 256, 0, stream>>>(A, dinv, dmaxf, Sq, Tq);
    k_gemm<<<256, 512, 0, stream>>>(Sq, Tq, dmaxf, theta, rowsumP, candV, candJ);
    k_dinv2<<<N / 256, 256, 0, stream>>>(rowsumP, dinv2);
    k_final<<<N, 64, 0, stream>>>(candV, candJ, dinv2, XW, b, kin, out);
}